// Round 1
// baseline (300.276 us; speedup 1.0000x reference)
//
#include <hip/hip_runtime.h>
#include <math.h>

// PersistentHomology: out = std(dist, ddof=1) / (mean(dist) + 1e-8)
// over the full 8192x8192 Euclidean distance matrix of 8192 fp32 points, D=128.
// Reduced to S1 = sum(dist), S2 = sum(dist^2) via the Gram trick; symmetry
// halves the work (upper-triangle tiles weighted 2x, diagonal tiles 1x).

#define NPTS   8192
#define DIM    128
#define TILE   128
#define LSTR   132              // padded LDS stride (floats): 16B-aligned, bank-spread
#define NTILES (NPTS / TILE)    // 64

__global__ __launch_bounds__(256)
void ph_pair_kernel(const float* __restrict__ x, double* __restrict__ partials)
{
    const int bi  = blockIdx.y;   // A-tile (rows)
    const int bj  = blockIdx.x;   // B-tile (cols)
    const int tid = threadIdx.x;
    const int flat = bi * NTILES + bj;

    if (bj < bi) {                // lower-triangle: covered by mirror, write zeros
        if (tid == 0) { partials[2*flat] = 0.0; partials[2*flat+1] = 0.0; }
        return;
    }

    __shared__ __align__(16) float As[TILE * LSTR];   // transposed: As[k*LSTR + row]
    __shared__ __align__(16) float Bs[TILE * LSTR];
    __shared__ float  nA[TILE];
    __shared__ float  nB[TILE];
    __shared__ double red1[256];
    __shared__ double red2[256];

    const float* Ab = x + (size_t)bi * TILE * DIM;
    const float* Bb = x + (size_t)bj * TILE * DIM;

    // ---- stage both 128x128 tiles into LDS, transposed ----
#pragma unroll
    for (int it = 0; it < 16; ++it) {
        const int e   = (tid + it * 256) * 4;   // element index within tile
        const int row = e >> 7;                 // e / 128
        const int k   = e & 127;
        float4 va = *reinterpret_cast<const float4*>(Ab + e);
        As[(k+0)*LSTR + row] = va.x;
        As[(k+1)*LSTR + row] = va.y;
        As[(k+2)*LSTR + row] = va.z;
        As[(k+3)*LSTR + row] = va.w;
        float4 vb = *reinterpret_cast<const float4*>(Bb + e);
        Bs[(k+0)*LSTR + row] = vb.x;
        Bs[(k+1)*LSTR + row] = vb.y;
        Bs[(k+2)*LSTR + row] = vb.z;
        Bs[(k+3)*LSTR + row] = vb.w;
    }
    __syncthreads();

    // ---- squared norms of the staged rows (free compute, saves a global pass) ----
    if (tid < 128) {
        float s = 0.f;
#pragma unroll 8
        for (int k = 0; k < DIM; ++k) { float v = As[k*LSTR + tid]; s = fmaf(v, v, s); }
        nA[tid] = s;
    } else {
        const int r = tid - 128;
        float s = 0.f;
#pragma unroll 8
        for (int k = 0; k < DIM; ++k) { float v = Bs[k*LSTR + r]; s = fmaf(v, v, s); }
        nB[r] = s;
    }
    __syncthreads();

    // ---- 8x8 register tile of dot products per thread ----
    const int tx = tid & 15, ty = tid >> 4;
    const int ra = ty * 8, cb = tx * 8;
    float acc[8][8];
#pragma unroll
    for (int r = 0; r < 8; ++r)
#pragma unroll
        for (int c = 0; c < 8; ++c) acc[r][c] = 0.f;

#pragma unroll 4
    for (int k = 0; k < DIM; ++k) {
        const float4 a0 = *reinterpret_cast<const float4*>(&As[k*LSTR + ra]);
        const float4 a1 = *reinterpret_cast<const float4*>(&As[k*LSTR + ra + 4]);
        const float4 b0 = *reinterpret_cast<const float4*>(&Bs[k*LSTR + cb]);
        const float4 b1 = *reinterpret_cast<const float4*>(&Bs[k*LSTR + cb + 4]);
        const float a[8] = {a0.x,a0.y,a0.z,a0.w,a1.x,a1.y,a1.z,a1.w};
        const float b[8] = {b0.x,b0.y,b0.z,b0.w,b1.x,b1.y,b1.z,b1.w};
#pragma unroll
        for (int r = 0; r < 8; ++r)
#pragma unroll
            for (int c = 0; c < 8; ++c)
                acc[r][c] = fmaf(a[r], b[c], acc[r][c]);
    }

    // ---- distances + per-thread sums (double) ----
    double s1 = 0.0, s2 = 0.0;
    const int gi0 = bi*TILE + ra, gj0 = bj*TILE + cb;
#pragma unroll
    for (int r = 0; r < 8; ++r) {
#pragma unroll
        for (int c = 0; c < 8; ++c) {
            float d2 = nA[ra+r] + nB[cb+c] - 2.0f * acc[r][c];
            d2 = fmaxf(d2, 0.0f);
            if (gi0 + r == gj0 + c) d2 = 0.0f;   // diagonal is exactly 0 in ref
            s1 += (double)sqrtf(d2);
            s2 += (double)d2;                    // dist^2 == clamped d2
        }
    }
    const double w = (bi == bj) ? 1.0 : 2.0;     // off-diagonal tiles cover (i,j)+(j,i)
    s1 *= w; s2 *= w;

    // ---- block reduction -> one deterministic partial per block ----
    red1[tid] = s1; red2[tid] = s2;
    __syncthreads();
    for (int off = 128; off > 0; off >>= 1) {
        if (tid < off) { red1[tid] += red1[tid+off]; red2[tid] += red2[tid+off]; }
        __syncthreads();
    }
    if (tid == 0) { partials[2*flat] = red1[0]; partials[2*flat+1] = red2[0]; }
}

__global__ __launch_bounds__(256)
void ph_finalize(const double* __restrict__ partials, float* __restrict__ out)
{
    __shared__ double r1[256], r2[256];
    const int tid = threadIdx.x;
    double s1 = 0.0, s2 = 0.0;
    for (int i = tid; i < NTILES*NTILES; i += 256) { s1 += partials[2*i]; s2 += partials[2*i+1]; }
    r1[tid] = s1; r2[tid] = s2;
    __syncthreads();
    for (int off = 128; off > 0; off >>= 1) {
        if (tid < off) { r1[tid] += r1[tid+off]; r2[tid] += r2[tid+off]; }
        __syncthreads();
    }
    if (tid == 0) {
        const double M    = (double)NPTS * (double)NPTS;
        const double mean = r1[0] / M;
        double var = (r2[0] - r1[0]*r1[0]/M) / (M - 1.0);   // ddof=1 over all M entries
        if (var < 0.0) var = 0.0;
        out[0] = (float)(sqrt(var) / (mean + 1e-8));
    }
}

extern "C" void kernel_launch(void* const* d_in, const int* in_sizes, int n_in,
                              void* d_out, int out_size, void* d_ws, size_t ws_size,
                              hipStream_t stream)
{
    const float* x   = (const float*)d_in[0];   // [8192, 128] fp32
    float* out       = (float*)d_out;           // 1 fp32 scalar
    double* partials = (double*)d_ws;           // 64*64*2*8 = 64 KiB scratch

    dim3 grid(NTILES, NTILES);
    ph_pair_kernel<<<grid, 256, 0, stream>>>(x, partials);
    ph_finalize<<<1, 256, 0, stream>>>(partials, out);
}

// Round 2
// 88.688 us; speedup vs baseline: 3.3857x; 3.3857x over previous
//
#include <hip/hip_runtime.h>
#include <hip/hip_bf16.h>
#include <math.h>

// PersistentHomology: out = std(dist, ddof=1) / (mean(dist) + 1e-8) over the
// 8192x8192 Euclidean distance matrix of 8192 fp32 points, D=128.
// S1 = sum(dist), S2 = sum(dist^2) via the Gram trick; symmetry halves work.
// Gram matrix via bf16 MFMA with hi/lo split: x = hi + lo (bf16 each),
// dot = hi.hi + hi.lo + lo.hi  (K = 3 segments of 128) -> ~fp32 accuracy.

#define NPTS   8192
#define DIM    128
#define TILE   128
#define NTILES (NPTS / TILE)    // 64

typedef __attribute__((ext_vector_type(8))) short short8;   // 8 bf16 (4 VGPRs)
typedef __attribute__((ext_vector_type(4))) float f32x4;    // MFMA accumulator

typedef const __attribute__((address_space(1))) void* gas_ptr;
typedef __attribute__((address_space(3))) void* las_ptr;

__device__ __forceinline__ void gload16(const void* g, void* l) {
    // DMA 16B/lane global->LDS; dest = wave-uniform base + lane*16
    __builtin_amdgcn_global_load_lds((gas_ptr)g, (las_ptr)l, 16, 0, 0);
}

// ---------------- prep: fp32 -> (hi, lo) bf16 split ----------------
__global__ __launch_bounds__(256)
void ph_convert(const float* __restrict__ x,
                ushort* __restrict__ hi, ushort* __restrict__ lo)
{
    const int i = (blockIdx.x * 256 + threadIdx.x) * 4;   // grid covers NPTS*DIM
    const float4 v = *reinterpret_cast<const float4*>(x + i);
    const float vv[4] = {v.x, v.y, v.z, v.w};
    ushort4 h, l;
    ushort hh[4], ll[4];
#pragma unroll
    for (int j = 0; j < 4; ++j) {
        __hip_bfloat16 hb = __float2bfloat16(vv[j]);
        float          hf = __bfloat162float(hb);
        __hip_bfloat16 lb = __float2bfloat16(vv[j] - hf);
        hh[j] = *reinterpret_cast<ushort*>(&hb);
        ll[j] = *reinterpret_cast<ushort*>(&lb);
    }
    h.x = hh[0]; h.y = hh[1]; h.z = hh[2]; h.w = hh[3];
    l.x = ll[0]; l.y = ll[1]; l.z = ll[2]; l.w = ll[3];
    *reinterpret_cast<ushort4*>(hi + i) = h;
    *reinterpret_cast<ushort4*>(lo + i) = l;
}

// ---------------- prep: fp32 squared row norms ----------------
__global__ __launch_bounds__(64)
void ph_norms(const float* __restrict__ x, float* __restrict__ sq)
{
    const int row  = blockIdx.x;
    const int lane = threadIdx.x;
    const float* p = x + (size_t)row * DIM;
    float a = p[lane], b = p[lane + 64];
    float s = fmaf(a, a, b * b);
#pragma unroll
    for (int off = 32; off > 0; off >>= 1) s += __shfl_down(s, off);
    if (lane == 0) sq[row] = s;
}

// ---------------- main: MFMA Gram tiles + distance reduction ----------------
// LDS tile layout (bf16, 256B rows), XOR-swizzled: phys_byte = row*256 + (kb ^ ((row&7)<<4))
__global__ __launch_bounds__(256)
void ph_mfma(const ushort* __restrict__ hi, const ushort* __restrict__ lo,
             const float* __restrict__ sq, double* __restrict__ partials)
{
    const int bi  = blockIdx.y;
    const int bj  = blockIdx.x;
    const int tid = threadIdx.x;
    const int flat = bi * NTILES + bj;

    if (bj < bi) {          // mirror covered; write deterministic zeros
        if (tid == 0) { partials[2*flat] = 0.0; partials[2*flat+1] = 0.0; }
        return;
    }

    __shared__ ushort As[TILE * TILE];   // 32 KB, swizzled
    __shared__ ushort Bs[TILE * TILE];   // 32 KB, swizzled
    __shared__ float  nA[TILE];
    __shared__ float  nB[TILE];
    __shared__ double red1[256];
    __shared__ double red2[256];

    if (tid < 128) nA[tid]       = sq[bi * TILE + tid];
    else           nB[tid - 128] = sq[bj * TILE + (tid - 128)];

    const int lane = tid & 63;
    const int wv   = tid >> 6;        // wave 0..3
    const int wr   = wv >> 1;         // wave row (0..1) -> 64 rows
    const int wc   = wv & 1;          // wave col (0..1) -> 64 cols

    f32x4 acc[4][4];
#pragma unroll
    for (int m = 0; m < 4; ++m)
#pragma unroll
        for (int n = 0; n < 4; ++n) acc[m][n] = (f32x4){0.f, 0.f, 0.f, 0.f};

    // dot = hi.hi + hi.lo + lo.hi
    const ushort* srcA[3] = { hi, hi, lo };
    const ushort* srcB[3] = { hi, lo, hi };

    // per-wave staging geometry: 8 chunks of 1KB per tile per wave
    const int srow = (lane >> 4);            // sub-row within chunk
    const int kbp  = (lane & 15) * 16;       // physical kb of this lane's 16B
#pragma unroll 1
    for (int seg = 0; seg < 3; ++seg) {
        const char* gA = (const char*)(srcA[seg] + (size_t)bi * TILE * DIM);
        const char* gB = (const char*)(srcB[seg] + (size_t)bj * TILE * DIM);
#pragma unroll
        for (int c = 0; c < 8; ++c) {
            const int chunk = wv * 8 + c;            // 0..31 (4 rows each)
            const int row   = chunk * 4 + srow;
            const int kbl   = kbp ^ ((row & 7) << 4);   // inverse swizzle on source
            const size_t goff = (size_t)row * 256 + kbl;
            gload16(gA + goff, (char*)As + chunk * 1024);
            gload16(gB + goff, (char*)Bs + chunk * 1024);
        }
        __syncthreads();   // drains vmcnt -> tiles ready

#pragma unroll
        for (int kk = 0; kk < 4; ++kk) {
            const int kb = kk * 64 + (lane >> 4) * 16;   // this lane's K-slice bytes
            short8 af[4], bfr[4];
#pragma unroll
            for (int m = 0; m < 4; ++m) {
                const int row = wr * 64 + m * 16 + (lane & 15);
                af[m] = *reinterpret_cast<const short8*>(
                    (const char*)As + row * 256 + (kb ^ ((row & 7) << 4)));
            }
#pragma unroll
            for (int n = 0; n < 4; ++n) {
                const int col = wc * 64 + n * 16 + (lane & 15);
                bfr[n] = *reinterpret_cast<const short8*>(
                    (const char*)Bs + col * 256 + (kb ^ ((col & 7) << 4)));
            }
#pragma unroll
            for (int m = 0; m < 4; ++m)
#pragma unroll
                for (int n = 0; n < 4; ++n)
                    acc[m][n] = __builtin_amdgcn_mfma_f32_16x16x32_bf16(
                        af[m], bfr[n], acc[m][n], 0, 0, 0);
        }
        __syncthreads();   // before next segment overwrites LDS
    }

    // ---- epilogue: distances + per-thread double sums ----
    double s1 = 0.0, s2 = 0.0;
#pragma unroll
    for (int m = 0; m < 4; ++m) {
#pragma unroll
        for (int n = 0; n < 4; ++n) {
#pragma unroll
            for (int r = 0; r < 4; ++r) {
                const int row = wr * 64 + m * 16 + (lane >> 4) * 4 + r;
                const int col = wc * 64 + n * 16 + (lane & 15);
                float d2 = nA[row] + nB[col] - 2.0f * acc[m][n][r];
                d2 = fmaxf(d2, 0.0f);
                if (bi * TILE + row == bj * TILE + col) d2 = 0.0f;  // exact 0 diagonal
                s1 += (double)sqrtf(d2);
                s2 += (double)d2;
            }
        }
    }
    const double w = (bi == bj) ? 1.0 : 2.0;
    red1[tid] = s1 * w; red2[tid] = s2 * w;
    __syncthreads();
    for (int off = 128; off > 0; off >>= 1) {
        if (tid < off) { red1[tid] += red1[tid+off]; red2[tid] += red2[tid+off]; }
        __syncthreads();
    }
    if (tid == 0) { partials[2*flat] = red1[0]; partials[2*flat+1] = red2[0]; }
}

// ---------------- finalize ----------------
__global__ __launch_bounds__(256)
void ph_finalize(const double* __restrict__ partials, float* __restrict__ out)
{
    __shared__ double r1[256], r2[256];
    const int tid = threadIdx.x;
    double s1 = 0.0, s2 = 0.0;
    for (int i = tid; i < NTILES*NTILES; i += 256) { s1 += partials[2*i]; s2 += partials[2*i+1]; }
    r1[tid] = s1; r2[tid] = s2;
    __syncthreads();
    for (int off = 128; off > 0; off >>= 1) {
        if (tid < off) { r1[tid] += r1[tid+off]; r2[tid] += r2[tid+off]; }
        __syncthreads();
    }
    if (tid == 0) {
        const double M    = (double)NPTS * (double)NPTS;
        const double mean = r1[0] / M;
        double var = (r2[0] - r1[0]*r1[0]/M) / (M - 1.0);
        if (var < 0.0) var = 0.0;
        out[0] = (float)(sqrt(var) / (mean + 1e-8));
    }
}

// ---------------- fp32 fallback (round-1, used only if ws too small) ----------------
#define LSTR 132
__global__ __launch_bounds__(256)
void ph_pair_kernel(const float* __restrict__ x, double* __restrict__ partials)
{
    const int bi  = blockIdx.y;
    const int bj  = blockIdx.x;
    const int tid = threadIdx.x;
    const int flat = bi * NTILES + bj;
    if (bj < bi) {
        if (tid == 0) { partials[2*flat] = 0.0; partials[2*flat+1] = 0.0; }
        return;
    }
    __shared__ __align__(16) float As[TILE * LSTR];
    __shared__ __align__(16) float Bs[TILE * LSTR];
    __shared__ float  nA[TILE];
    __shared__ float  nB[TILE];
    __shared__ double red1[256];
    __shared__ double red2[256];
    const float* Ab = x + (size_t)bi * TILE * DIM;
    const float* Bb = x + (size_t)bj * TILE * DIM;
#pragma unroll
    for (int it = 0; it < 16; ++it) {
        const int e   = (tid + it * 256) * 4;
        const int row = e >> 7;
        const int k   = e & 127;
        float4 va = *reinterpret_cast<const float4*>(Ab + e);
        As[(k+0)*LSTR + row] = va.x; As[(k+1)*LSTR + row] = va.y;
        As[(k+2)*LSTR + row] = va.z; As[(k+3)*LSTR + row] = va.w;
        float4 vb = *reinterpret_cast<const float4*>(Bb + e);
        Bs[(k+0)*LSTR + row] = vb.x; Bs[(k+1)*LSTR + row] = vb.y;
        Bs[(k+2)*LSTR + row] = vb.z; Bs[(k+3)*LSTR + row] = vb.w;
    }
    __syncthreads();
    if (tid < 128) {
        float s = 0.f;
#pragma unroll 8
        for (int k = 0; k < DIM; ++k) { float v = As[k*LSTR + tid]; s = fmaf(v, v, s); }
        nA[tid] = s;
    } else {
        const int r = tid - 128;
        float s = 0.f;
#pragma unroll 8
        for (int k = 0; k < DIM; ++k) { float v = Bs[k*LSTR + r]; s = fmaf(v, v, s); }
        nB[r] = s;
    }
    __syncthreads();
    const int tx = tid & 15, ty = tid >> 4;
    const int ra = ty * 8, cb = tx * 8;
    float acc[8][8];
#pragma unroll
    for (int r = 0; r < 8; ++r)
#pragma unroll
        for (int c = 0; c < 8; ++c) acc[r][c] = 0.f;
#pragma unroll 4
    for (int k = 0; k < DIM; ++k) {
        const float4 a0 = *reinterpret_cast<const float4*>(&As[k*LSTR + ra]);
        const float4 a1 = *reinterpret_cast<const float4*>(&As[k*LSTR + ra + 4]);
        const float4 b0 = *reinterpret_cast<const float4*>(&Bs[k*LSTR + cb]);
        const float4 b1 = *reinterpret_cast<const float4*>(&Bs[k*LSTR + cb + 4]);
        const float a[8] = {a0.x,a0.y,a0.z,a0.w,a1.x,a1.y,a1.z,a1.w};
        const float b[8] = {b0.x,b0.y,b0.z,b0.w,b1.x,b1.y,b1.z,b1.w};
#pragma unroll
        for (int r = 0; r < 8; ++r)
#pragma unroll
            for (int c = 0; c < 8; ++c)
                acc[r][c] = fmaf(a[r], b[c], acc[r][c]);
    }
    double s1 = 0.0, s2 = 0.0;
    const int gi0 = bi*TILE + ra, gj0 = bj*TILE + cb;
#pragma unroll
    for (int r = 0; r < 8; ++r) {
#pragma unroll
        for (int c = 0; c < 8; ++c) {
            float d2 = nA[ra+r] + nB[cb+c] - 2.0f * acc[r][c];
            d2 = fmaxf(d2, 0.0f);
            if (gi0 + r == gj0 + c) d2 = 0.0f;
            s1 += (double)sqrtf(d2);
            s2 += (double)d2;
        }
    }
    const double w = (bi == bj) ? 1.0 : 2.0;
    s1 *= w; s2 *= w;
    red1[tid] = s1; red2[tid] = s2;
    __syncthreads();
    for (int off = 128; off > 0; off >>= 1) {
        if (tid < off) { red1[tid] += red1[tid+off]; red2[tid] += red2[tid+off]; }
        __syncthreads();
    }
    if (tid == 0) { partials[2*flat] = red1[0]; partials[2*flat+1] = red2[0]; }
}

extern "C" void kernel_launch(void* const* d_in, const int* in_sizes, int n_in,
                              void* d_out, int out_size, void* d_ws, size_t ws_size,
                              hipStream_t stream)
{
    const float* x = (const float*)d_in[0];   // [8192, 128] fp32
    float* out     = (float*)d_out;

    // ws layout: hi (2MB) | lo (2MB) | sq (32KB) | partials (64KB)
    const size_t HI_OFF = 0;
    const size_t LO_OFF = (size_t)NPTS * DIM * sizeof(ushort);          // 2 MB
    const size_t SQ_OFF = 2 * LO_OFF;                                   // 4 MB
    const size_t PT_OFF = SQ_OFF + NPTS * sizeof(float);                // +32 KB
    const size_t NEEDED = PT_OFF + (size_t)NTILES * NTILES * 2 * sizeof(double);

    if (ws_size >= NEEDED) {
        ushort* hi       = (ushort*)((char*)d_ws + HI_OFF);
        ushort* lo       = (ushort*)((char*)d_ws + LO_OFF);
        float*  sq       = (float*) ((char*)d_ws + SQ_OFF);
        double* partials = (double*)((char*)d_ws + PT_OFF);

        ph_convert<<<(NPTS * DIM) / (256 * 4), 256, 0, stream>>>(x, hi, lo);
        ph_norms<<<NPTS, 64, 0, stream>>>(x, sq);
        ph_mfma<<<dim3(NTILES, NTILES), 256, 0, stream>>>(hi, lo, sq, partials);
        ph_finalize<<<1, 256, 0, stream>>>(partials, out);
    } else {
        double* partials = (double*)d_ws;     // 64 KB
        ph_pair_kernel<<<dim3(NTILES, NTILES), 256, 0, stream>>>(x, partials);
        ph_finalize<<<1, 256, 0, stream>>>(partials, out);
    }
}

// Round 3
// 41.817 us; speedup vs baseline: 7.1807x; 2.1209x over previous
//
#include <hip/hip_runtime.h>
#include <hip/hip_bf16.h>
#include <math.h>

// PersistentHomology: out = std(dist, ddof=1) / (mean(dist) + 1e-8) over the
// 8192x8192 Euclidean distance matrix of 8192 fp32 points, D=128.
// S1 = sum(dist), S2 = sum(dist^2); symmetry -> 2080 upper-triangle 128^2 tiles.
// Gram via pure-bf16 MFMA (error analysis: random +-3e-3 per dist averages out;
// final error ~1e-4 << 1.27e-3 threshold). Norms stay exact fp32.

#define NPTS   8192
#define DIM    128
#define TILE   128
#define KHALF  64                 // K elements staged per LDS phase
#define NTILES (NPTS / TILE)      // 64
#define NTOT   (NTILES * (NTILES + 1) / 2)   // 2080 upper-tri tiles

typedef __attribute__((ext_vector_type(8))) short short8;   // 8 bf16
typedef __attribute__((ext_vector_type(4))) float f32x4;    // MFMA accumulator

typedef const __attribute__((address_space(1))) void* gas_ptr;
typedef __attribute__((address_space(3))) void* las_ptr;

__device__ __forceinline__ void gload16(const void* g, void* l) {
    // DMA 16B/lane global->LDS; LDS dest = wave-uniform base + lane*16
    __builtin_amdgcn_global_load_lds((gas_ptr)g, (las_ptr)l, 16, 0, 0);
}

// ---------------- prep: fp32 -> bf16 + fp32 squared norms (fused) ----------------
__global__ __launch_bounds__(256)
void ph_prep(const float* __restrict__ x, ushort* __restrict__ xb,
             float* __restrict__ sq)
{
    const int tid = threadIdx.x;
    const int row = blockIdx.x * 32 + (tid >> 3);
    const int seg = tid & 7;                       // 16 elems per thread
    const float4* p = reinterpret_cast<const float4*>(x + (size_t)row * DIM + seg * 16);
    float v[16];
    {
        float4 a = p[0], b = p[1], c = p[2], d = p[3];
        v[0]=a.x; v[1]=a.y; v[2]=a.z; v[3]=a.w;  v[4]=b.x; v[5]=b.y; v[6]=b.z; v[7]=b.w;
        v[8]=c.x; v[9]=c.y; v[10]=c.z; v[11]=c.w; v[12]=d.x; v[13]=d.y; v[14]=d.z; v[15]=d.w;
    }
    float s = 0.f;
    ushort h[16];
#pragma unroll
    for (int j = 0; j < 16; ++j) {
        __hip_bfloat16 hb = __float2bfloat16(v[j]);
        h[j] = *reinterpret_cast<ushort*>(&hb);
        s = fmaf(v[j], v[j], s);
    }
    short8 o0, o1;
#pragma unroll
    for (int j = 0; j < 8; ++j) { o0[j] = (short)h[j]; o1[j] = (short)h[j+8]; }
    short8* dst = reinterpret_cast<short8*>(xb + (size_t)row * DIM + seg * 16);
    dst[0] = o0; dst[1] = o1;
    // reduce norm across the 8 lanes sharing this row (lanes differ in bits 0..2)
    s += __shfl_xor(s, 1); s += __shfl_xor(s, 2); s += __shfl_xor(s, 4);
    if (seg == 0) sq[row] = s;
}

// ---------------- main: bf16 MFMA Gram tiles + distance reduction ----------------
// LDS half-tile layout: 128 rows x 128B, swizzled: phys = row*128 + (kb ^ ((row&7)<<4))
__global__ __launch_bounds__(256)
void ph_gram(const ushort* __restrict__ xb, const float* __restrict__ sq,
             double* __restrict__ partials)
{
    const int f   = blockIdx.x;          // 0..NTOT-1
    const int tid = threadIdx.x;

    // decode flat -> (bi, bj), bi <= bj ; T(r) = r*64 - r*(r-1)/2
    int bi = (int)((129.0f - sqrtf((float)(16641 - 8 * f))) * 0.5f);
    while ((bi + 1) * 64 - ((bi + 1) * bi) / 2 <= f) ++bi;
    while (bi * 64 - (bi * (bi - 1)) / 2 > f) --bi;
    const int bj = bi + (f - (bi * 64 - (bi * (bi - 1)) / 2));

    __shared__ ushort As[TILE * KHALF];   // 16 KB
    __shared__ ushort Bs[TILE * KHALF];   // 16 KB
    __shared__ float  nA[TILE], nB[TILE];
    __shared__ double rr[8];

    const int lane = tid & 63;
    const int wv   = tid >> 6;           // wave 0..3
    const int wr   = wv >> 1, wc = wv & 1;

    if (tid < 128) nA[tid]       = sq[bi * TILE + tid];
    else           nB[tid - 128] = sq[bj * TILE + (tid - 128)];

    const char* gA = (const char*)(xb + (size_t)bi * TILE * DIM);
    const char* gB = (const char*)(xb + (size_t)bj * TILE * DIM);

    // stage K-half h: per wave 4x 1KB chunks per tile (lane l -> chunk*1024 + l*16)
    const int srow = lane >> 3;                    // 0..7 within chunk
    const int skb  = (lane & 7) * 16;              // 16B slot within 128B row
#define STAGE(h)                                                              \
    {                                                                         \
        _Pragma("unroll")                                                     \
        for (int c = 0; c < 4; ++c) {                                         \
            const int chunk = wv * 4 + c;                                     \
            const int row   = chunk * 8 + srow;                               \
            const int gkb   = (h) * 128 + (skb ^ ((row & 7) << 4));           \
            const size_t go = (size_t)row * 256 + gkb;                        \
            gload16(gA + go, (char*)As + chunk * 1024);                       \
            gload16(gB + go, (char*)Bs + chunk * 1024);                       \
        }                                                                     \
    }

    f32x4 acc[4][4];
#pragma unroll
    for (int m = 0; m < 4; ++m)
#pragma unroll
        for (int n = 0; n < 4; ++n) acc[m][n] = (f32x4){0.f, 0.f, 0.f, 0.f};

    STAGE(0);
    __syncthreads();

#pragma unroll
    for (int h = 0; h < 2; ++h) {
#pragma unroll
        for (int kk = 0; kk < 2; ++kk) {
            const int kb = kk * 64 + (lane >> 4) * 16;   // byte k-slice in half-row
            short8 af[4], bfr[4];
#pragma unroll
            for (int m = 0; m < 4; ++m) {
                const int row = wr * 64 + m * 16 + (lane & 15);
                af[m] = *reinterpret_cast<const short8*>(
                    (const char*)As + row * 128 + (kb ^ ((row & 7) << 4)));
            }
#pragma unroll
            for (int n = 0; n < 4; ++n) {
                const int col = wc * 64 + n * 16 + (lane & 15);
                bfr[n] = *reinterpret_cast<const short8*>(
                    (const char*)Bs + col * 128 + (kb ^ ((col & 7) << 4)));
            }
#pragma unroll
            for (int m = 0; m < 4; ++m)
#pragma unroll
                for (int n = 0; n < 4; ++n)
                    acc[m][n] = __builtin_amdgcn_mfma_f32_16x16x32_bf16(
                        af[m], bfr[n], acc[m][n], 0, 0, 0);
        }
        if (h == 0) {
            __syncthreads();      // done reading half 0
            STAGE(1);
            __syncthreads();      // half 1 ready
        }
    }

    // ---- epilogue: distances, fp32 sums, wave-tree reduce ----
    float s1 = 0.f, s2 = 0.f;
    const bool diag = (bi == bj);
#pragma unroll
    for (int m = 0; m < 4; ++m) {
        float nAr[4];
#pragma unroll
        for (int r = 0; r < 4; ++r) nAr[r] = nA[wr*64 + m*16 + (lane>>4)*4 + r];
#pragma unroll
        for (int n = 0; n < 4; ++n) {
            const int col  = wc*64 + n*16 + (lane & 15);
            const float nBc = nB[col];
#pragma unroll
            for (int r = 0; r < 4; ++r) {
                float d2 = fmaf(-2.f, acc[m][n][r], nAr[r] + nBc);
                d2 = fmaxf(d2, 0.f);
                if (diag) {
                    const int row = wr*64 + m*16 + (lane>>4)*4 + r;
                    if (row == col) d2 = 0.f;    // exact-0 diagonal like ref
                }
                s1 += sqrtf(d2);
                s2 += d2;
            }
        }
    }
#pragma unroll
    for (int off = 1; off < 64; off <<= 1) {
        s1 += __shfl_xor(s1, off);
        s2 += __shfl_xor(s2, off);
    }
    const double w = diag ? 1.0 : 2.0;
    if (lane == 0) { rr[wv] = (double)s1 * w; rr[4 + wv] = (double)s2 * w; }
    __syncthreads();
    if (tid == 0) {
        partials[2*f]     = rr[0] + rr[1] + rr[2] + rr[3];
        partials[2*f + 1] = rr[4] + rr[5] + rr[6] + rr[7];
    }
#undef STAGE
}

// ---------------- finalize ----------------
__global__ __launch_bounds__(256)
void ph_finalize(const double* __restrict__ partials, float* __restrict__ out)
{
    __shared__ double r1[256], r2[256];
    const int tid = threadIdx.x;
    double s1 = 0.0, s2 = 0.0;
    for (int i = tid; i < NTOT; i += 256) { s1 += partials[2*i]; s2 += partials[2*i+1]; }
    r1[tid] = s1; r2[tid] = s2;
    __syncthreads();
    for (int off = 128; off > 0; off >>= 1) {
        if (tid < off) { r1[tid] += r1[tid+off]; r2[tid] += r2[tid+off]; }
        __syncthreads();
    }
    if (tid == 0) {
        const double M    = (double)NPTS * (double)NPTS;
        const double mean = r1[0] / M;
        double var = (r2[0] - r1[0]*r1[0]/M) / (M - 1.0);
        if (var < 0.0) var = 0.0;
        out[0] = (float)(sqrt(var) / (mean + 1e-8));
    }
}

// ---------------- fp32 fallback (only if ws too small) ----------------
#define LSTR 132
__global__ __launch_bounds__(256)
void ph_pair_kernel(const float* __restrict__ x, double* __restrict__ partials)
{
    const int bi  = blockIdx.y;
    const int bj  = blockIdx.x;
    const int tid = threadIdx.x;
    const int flat = bi * NTILES + bj;
    if (bj < bi) {
        if (tid == 0) { partials[2*flat] = 0.0; partials[2*flat+1] = 0.0; }
        return;
    }
    __shared__ __align__(16) float As[TILE * LSTR];
    __shared__ __align__(16) float Bs[TILE * LSTR];
    __shared__ float  nA[TILE];
    __shared__ float  nB[TILE];
    __shared__ double red1[256];
    __shared__ double red2[256];
    const float* Ab = x + (size_t)bi * TILE * DIM;
    const float* Bb = x + (size_t)bj * TILE * DIM;
#pragma unroll
    for (int it = 0; it < 16; ++it) {
        const int e   = (tid + it * 256) * 4;
        const int row = e >> 7;
        const int k   = e & 127;
        float4 va = *reinterpret_cast<const float4*>(Ab + e);
        As[(k+0)*LSTR + row] = va.x; As[(k+1)*LSTR + row] = va.y;
        As[(k+2)*LSTR + row] = va.z; As[(k+3)*LSTR + row] = va.w;
        float4 vb = *reinterpret_cast<const float4*>(Bb + e);
        Bs[(k+0)*LSTR + row] = vb.x; Bs[(k+1)*LSTR + row] = vb.y;
        Bs[(k+2)*LSTR + row] = vb.z; Bs[(k+3)*LSTR + row] = vb.w;
    }
    __syncthreads();
    if (tid < 128) {
        float s = 0.f;
#pragma unroll 8
        for (int k = 0; k < DIM; ++k) { float v = As[k*LSTR + tid]; s = fmaf(v, v, s); }
        nA[tid] = s;
    } else {
        const int r = tid - 128;
        float s = 0.f;
#pragma unroll 8
        for (int k = 0; k < DIM; ++k) { float v = Bs[k*LSTR + r]; s = fmaf(v, v, s); }
        nB[r] = s;
    }
    __syncthreads();
    const int tx = tid & 15, ty = tid >> 4;
    const int ra = ty * 8, cb = tx * 8;
    float acc[8][8];
#pragma unroll
    for (int r = 0; r < 8; ++r)
#pragma unroll
        for (int c = 0; c < 8; ++c) acc[r][c] = 0.f;
#pragma unroll 4
    for (int k = 0; k < DIM; ++k) {
        const float4 a0 = *reinterpret_cast<const float4*>(&As[k*LSTR + ra]);
        const float4 a1 = *reinterpret_cast<const float4*>(&As[k*LSTR + ra + 4]);
        const float4 b0 = *reinterpret_cast<const float4*>(&Bs[k*LSTR + cb]);
        const float4 b1 = *reinterpret_cast<const float4*>(&Bs[k*LSTR + cb + 4]);
        const float a[8] = {a0.x,a0.y,a0.z,a0.w,a1.x,a1.y,a1.z,a1.w};
        const float b[8] = {b0.x,b0.y,b0.z,b0.w,b1.x,b1.y,b1.z,b1.w};
#pragma unroll
        for (int r = 0; r < 8; ++r)
#pragma unroll
            for (int c = 0; c < 8; ++c)
                acc[r][c] = fmaf(a[r], b[c], acc[r][c]);
    }
    double s1 = 0.0, s2 = 0.0;
    const int gi0 = bi*TILE + ra, gj0 = bj*TILE + cb;
#pragma unroll
    for (int r = 0; r < 8; ++r) {
#pragma unroll
        for (int c = 0; c < 8; ++c) {
            float d2 = nA[ra+r] + nB[cb+c] - 2.0f * acc[r][c];
            d2 = fmaxf(d2, 0.0f);
            if (gi0 + r == gj0 + c) d2 = 0.0f;
            s1 += (double)sqrtf(d2);
            s2 += (double)d2;
        }
    }
    const double w = (bi == bj) ? 1.0 : 2.0;
    s1 *= w; s2 *= w;
    red1[tid] = s1; red2[tid] = s2;
    __syncthreads();
    for (int off = 128; off > 0; off >>= 1) {
        if (tid < off) { red1[tid] += red1[tid+off]; red2[tid] += red2[tid+off]; }
        __syncthreads();
    }
    if (tid == 0) { partials[2*flat] = red1[0]; partials[2*flat+1] = red2[0]; }
}

__global__ __launch_bounds__(256)
void ph_finalize_sq(const double* __restrict__ partials, float* __restrict__ out)
{
    __shared__ double r1[256], r2[256];
    const int tid = threadIdx.x;
    double s1 = 0.0, s2 = 0.0;
    for (int i = tid; i < NTILES*NTILES; i += 256) { s1 += partials[2*i]; s2 += partials[2*i+1]; }
    r1[tid] = s1; r2[tid] = s2;
    __syncthreads();
    for (int off = 128; off > 0; off >>= 1) {
        if (tid < off) { r1[tid] += r1[tid+off]; r2[tid] += r2[tid+off]; }
        __syncthreads();
    }
    if (tid == 0) {
        const double M    = (double)NPTS * (double)NPTS;
        const double mean = r1[0] / M;
        double var = (r2[0] - r1[0]*r1[0]/M) / (M - 1.0);
        if (var < 0.0) var = 0.0;
        out[0] = (float)(sqrt(var) / (mean + 1e-8));
    }
}

extern "C" void kernel_launch(void* const* d_in, const int* in_sizes, int n_in,
                              void* d_out, int out_size, void* d_ws, size_t ws_size,
                              hipStream_t stream)
{
    const float* x = (const float*)d_in[0];   // [8192, 128] fp32
    float* out     = (float*)d_out;

    // ws layout: xb bf16 (2MB) | sq (32KB) | partials (NTOT*2*8)
    const size_t XB_OFF = 0;
    const size_t SQ_OFF = (size_t)NPTS * DIM * sizeof(ushort);   // 2 MB
    const size_t PT_OFF = SQ_OFF + NPTS * sizeof(float);
    const size_t NEEDED = PT_OFF + (size_t)NTOT * 2 * sizeof(double);

    if (ws_size >= NEEDED) {
        ushort* xb       = (ushort*)((char*)d_ws + XB_OFF);
        float*  sq       = (float*) ((char*)d_ws + SQ_OFF);
        double* partials = (double*)((char*)d_ws + PT_OFF);

        ph_prep<<<NPTS / 32, 256, 0, stream>>>(x, xb, sq);
        ph_gram<<<NTOT, 256, 0, stream>>>(xb, sq, partials);
        ph_finalize<<<1, 256, 0, stream>>>(partials, out);
    } else {
        double* partials = (double*)d_ws;
        ph_pair_kernel<<<dim3(NTILES, NTILES), 256, 0, stream>>>(x, partials);
        ph_finalize_sq<<<1, 256, 0, stream>>>(partials, out);
    }
}